// Round 1
// baseline (743.567 us; speedup 1.0000x reference)
//
#include <hip/hip_runtime.h>

// CRF forward algorithm (log partition function) on MI355X.
// B=256 batches, T=2048 timesteps, N=64 tags.
//
// Strategy (round 0): linear-space recurrence with exact power-of-2
// renormalization. One wave per batch; lane j owns tag j. Etrans row j lives
// in 64 VGPRs per lane; p[k] broadcast via v_readlane feeding v_fmac.
// exp(unary) hoisted out of the serial chain via 4-step prefetch groups.

namespace {
constexpr int kB = 256;
constexpr int kT = 2048;
constexpr int kN = 64;
constexpr int kStart = 1;  // GO
constexpr int kEnd = 2;    // EOS
}  // namespace

__device__ __forceinline__ float lane_bcast(float v, int lane) {
  return __int_as_float(__builtin_amdgcn_readlane(__float_as_int(v), lane));
}

// One recurrence step in linear space:
//   q[j] = sum_k Etrans[j][k] * p[k];  p'[j] = q[j] * exp(unary[t][j])
// e_row is lane j's row of Etrans (registers). u is unary[t][j] for this lane.
__device__ __forceinline__ float crf_step(float p, const float (&e_row)[kN], float u) {
  float a0 = 0.f, a1 = 0.f, a2 = 0.f, a3 = 0.f;
#pragma unroll
  for (int k = 0; k < kN; k += 4) {
    a0 = fmaf(e_row[k + 0], lane_bcast(p, k + 0), a0);
    a1 = fmaf(e_row[k + 1], lane_bcast(p, k + 1), a1);
    a2 = fmaf(e_row[k + 2], lane_bcast(p, k + 2), a2);
    a3 = fmaf(e_row[k + 3], lane_bcast(p, k + 3), a3);
  }
  float q = (a0 + a1) + (a2 + a3);
  return q * __expf(u);
}

__global__ __launch_bounds__(64, 1) void crf_forward_kernel(
    const float* __restrict__ unary, const float* __restrict__ trans,
    const int* __restrict__ lengths, float* __restrict__ out) {
  const int b = blockIdx.x;
  const int j = threadIdx.x;  // lane == tag index

  const int len = lengths[b];  // in [T/2, T]

  // Etrans row j into registers: e_row[k] = exp(trans[j][k]).
  float e_row[kN];
#pragma unroll
  for (int k = 0; k < kN; ++k) e_row[k] = __expf(trans[j * kN + k]);

  // p one-hot at START tag. Matches reference: NEG_INF entries contribute
  // exactly 0 after max-subtracted LSE in fp32.
  float p = (j == kStart) ? 1.0f : 0.0f;
  float tot_e = 0.0f;  // accumulated log2-shift (integer-valued, exact in fp32)

  const float* ub = unary + (size_t)b * kT * kN + j;

  const int G = len >> 2;  // full groups of 4 steps (len >= 1024 so G >= 256)
  const int R = len & 3;

  // Preload group 0 (t = 0..3).
  float n0 = ub[(size_t)0 * kN];
  float n1 = ub[(size_t)1 * kN];
  float n2 = ub[(size_t)2 * kN];
  float n3 = ub[(size_t)3 * kN];

  for (int g = 0; g < G; ++g) {
    const float c0 = n0, c1 = n1, c2 = n2, c3 = n3;

    // Prefetch next group's unary (clamped to stay in-bounds; clamped reads
    // are never consumed).
    const int tp = (g + 1) << 2;
    const int t0 = (tp + 0 < kT) ? tp + 0 : kT - 1;
    const int t1 = (tp + 1 < kT) ? tp + 1 : kT - 1;
    const int t2 = (tp + 2 < kT) ? tp + 2 : kT - 1;
    const int t3 = (tp + 3 < kT) ? tp + 3 : kT - 1;
    n0 = ub[(size_t)t0 * kN];
    n1 = ub[(size_t)t1 * kN];
    n2 = ub[(size_t)t2 * kN];
    n3 = ub[(size_t)t3 * kN];

    p = crf_step(p, e_row, c0);
    p = crf_step(p, e_row, c1);
    p = crf_step(p, e_row, c2);
    p = crf_step(p, e_row, c3);

    // Renormalize by exact power of 2 every 4 steps.
    // Worst-case growth ~2^15/step => <2^62 over a group + 2^6 in the sum:
    // no overflow. Entries underflowing are >= ~87 nats below max: negligible.
    float m = p;
#pragma unroll
    for (int mask = 32; mask; mask >>= 1) m = fmaxf(m, __shfl_xor(m, mask));
    const int e = (int)((__float_as_uint(m) >> 23) & 0xFF) - 127;
    p *= __uint_as_float((unsigned)(127 - e) << 23);  // exact 2^-e
    tot_e += (float)e;
  }

  // Tail steps (R in 0..3); values already prefetched into n0..n2.
  if (R > 0) p = crf_step(p, e_row, n0);
  if (R > 1) p = crf_step(p, e_row, n1);
  if (R > 2) p = crf_step(p, e_row, n2);

  // Terminal: out[b] = tot_e*ln2 + ln( sum_k p[k] * exp(trans[END][k]) )
  float term = p * __expf(trans[kEnd * kN + j]);
#pragma unroll
  for (int mask = 32; mask; mask >>= 1) term += __shfl_xor(term, mask);

  if (j == 0) out[b] = tot_e * 0.69314718055994530942f + logf(term);
}

extern "C" void kernel_launch(void* const* d_in, const int* in_sizes, int n_in,
                              void* d_out, int out_size, void* d_ws, size_t ws_size,
                              hipStream_t stream) {
  const float* unary = (const float*)d_in[0];    // [B, T, N] fp32
  const float* trans = (const float*)d_in[1];    // [N, N] fp32
  const int* lengths = (const int*)d_in[2];      // [B] int32
  float* out = (float*)d_out;                    // [B] fp32

  crf_forward_kernel<<<dim3(kB), dim3(kN), 0, stream>>>(unary, trans, lengths, out);
}

// Round 2
// 524.927 us; speedup vs baseline: 1.4165x; 1.4165x over previous
//
#include <hip/hip_runtime.h>

// CRF forward (log partition), B=256, T=2048, N=64, MI355X.
//
// Round 2: MFMA-based recurrence with permuted-K A-fragments so the
// C-layout output feeds back as the B operand with ZERO cross-lane moves.
//   p_{t+1} = (Etrans · p_t) ⊙ exp(unary[t])      (linear space)
// exp(unary) precomputed by a bandwidth-bound pre-pass. Exact power-of-2
// renormalization every 4 steps; log-scale accumulated in tot_e.

typedef __attribute__((ext_vector_type(4))) float f32x4;
typedef __attribute__((ext_vector_type(8))) short bf16x8;

namespace {
constexpr int kB = 256;
constexpr int kT = 2048;
constexpr int kN = 64;
constexpr int kStart = 1;  // GO
constexpr int kEnd = 2;    // EOS
}  // namespace

// ---------------- pre-pass: eu = exp(unary), elementwise ----------------
__global__ void exp_pass_kernel(const float* __restrict__ in,
                                float* __restrict__ out, int n4) {
  int i = blockIdx.x * blockDim.x + threadIdx.x;
  const int stride = gridDim.x * blockDim.x;
  for (; i < n4; i += stride) {
    f32x4 v = ((const f32x4*)in)[i];
    f32x4 r;
    r.x = __expf(v.x);
    r.y = __expf(v.y);
    r.z = __expf(v.z);
    r.w = __expf(v.w);
    ((f32x4*)out)[i] = r;
  }
}

// pack two f32 into one u32 holding {bf16(hi) : bf16(lo)} (truncation).
__device__ __forceinline__ unsigned pack2bf(float lo, float hi) {
  // v_perm_b32: result = bytes {a.b3,a.b2,b.b3,b.b2} -> high16 from a, low16 from b.
  return __builtin_amdgcn_perm(__float_as_uint(hi), __float_as_uint(lo), 0x07060302u);
}

// B-fragment for k-chunk kc from C-layout regs: element j<4 <- lo[r=j],
// j>=4 <- hi[r=j&3]. Matches psi(kc,j) = (2kc+(j>>2))*16 + q4*4 + (j&3).
__device__ __forceinline__ bf16x8 pack_bfrag(f32x4 lo, f32x4 hi) {
  union { unsigned u[4]; bf16x8 s; } r;
  r.u[0] = pack2bf(lo.x, lo.y);
  r.u[1] = pack2bf(lo.z, lo.w);
  r.u[2] = pack2bf(hi.x, hi.y);
  r.u[3] = pack2bf(hi.z, hi.w);
  return r.s;
}

__device__ __forceinline__ f32x4 max4(f32x4 a, f32x4 b) {
  f32x4 r;
  r.x = fmaxf(a.x, b.x);
  r.y = fmaxf(a.y, b.y);
  r.z = fmaxf(a.z, b.z);
  r.w = fmaxf(a.w, b.w);
  return r;
}

__global__ __launch_bounds__(64, 1) void crf_mfma_kernel(
    const float* __restrict__ eu, const float* __restrict__ trans,
    const int* __restrict__ lengths, float* __restrict__ out) {
  const int b = blockIdx.x;
  const int lane = threadIdx.x;
  const int col = lane & 15;
  const int q4 = lane >> 4;
  const int len = lengths[b];

  // Static A-fragments: A[m][psi(slot)] = exp(trans[m][k]), bf16, RNE via +0x8000.
  bf16x8 afrag[4][2];
#pragma unroll
  for (int mt = 0; mt < 4; ++mt) {
#pragma unroll
    for (int kc = 0; kc < 2; ++kc) {
      union { unsigned u[4]; bf16x8 s; } fr;
#pragma unroll
      for (int jp = 0; jp < 4; ++jp) {
        const int j0 = 2 * jp, j1 = 2 * jp + 1;
        const int k0 = (2 * kc + (j0 >> 2)) * 16 + q4 * 4 + (j0 & 3);
        const int k1 = (2 * kc + (j1 >> 2)) * 16 + q4 * 4 + (j1 & 3);
        unsigned e0 = __float_as_uint(__expf(trans[(mt * 16 + col) * kN + k0])) + 0x8000u;
        unsigned e1 = __float_as_uint(__expf(trans[(mt * 16 + col) * kN + k1])) + 0x8000u;
        fr.u[jp] = __builtin_amdgcn_perm(e1, e0, 0x07060302u);
      }
      afrag[mt][kc] = fr.s;
    }
  }

  // exp(trans[END][row]) in C layout.
  float eend[4][4];
#pragma unroll
  for (int mt = 0; mt < 4; ++mt)
#pragma unroll
    for (int r = 0; r < 4; ++r)
      eend[mt][r] = __expf(trans[kEnd * kN + mt * 16 + q4 * 4 + r]);

  // p in C layout (replicated across the 16 columns). One-hot at START=1
  // -> mt=0, q4=0, r=1.
  f32x4 ps[4];
#pragma unroll
  for (int mt = 0; mt < 4; ++mt) ps[mt] = (f32x4){0.f, 0.f, 0.f, 0.f};
  if (q4 == 0) ps[0].y = 1.0f;

  // eu prefetch ring, depth 4 (eu is L3-resident after the pre-pass).
  const float* ep = eu + (size_t)b * kT * kN + q4 * 4;
  f32x4 pre[4][4];
#pragma unroll
  for (int i = 0; i < 4; ++i)
#pragma unroll
    for (int mt = 0; mt < 4; ++mt)
      pre[i][mt] = *(const f32x4*)(ep + i * kN + mt * 16);

  const float* epn = ep + 4 * kN;
  int tnext = 4;
  float tot_e = 0.0f;

  const int G = len >> 2;
  const int R = len & 3;
  const f32x4 z4 = {0.f, 0.f, 0.f, 0.f};

  for (int g = 0; g < G; ++g) {
#pragma unroll
    for (int i = 0; i < 4; ++i) {
      const f32x4 e0 = pre[i][0], e1 = pre[i][1], e2 = pre[i][2], e3 = pre[i][3];
      // Refill slot i for step t = tnext (clamped; clamped rows never consumed).
      pre[i][0] = *(const f32x4*)(epn);
      pre[i][1] = *(const f32x4*)(epn + 16);
      pre[i][2] = *(const f32x4*)(epn + 32);
      pre[i][3] = *(const f32x4*)(epn + 48);
      ++tnext;
      if (tnext < kT) epn += kN;

      // One recurrence step: q = E·p (8 MFMA), then p = q ⊙ eu.
      const bf16x8 b0 = pack_bfrag(ps[0], ps[1]);
      const bf16x8 b1 = pack_bfrag(ps[2], ps[3]);

      f32x4 q0 = __builtin_amdgcn_mfma_f32_16x16x32_bf16(afrag[0][0], b0, z4, 0, 0, 0);
      f32x4 q1 = __builtin_amdgcn_mfma_f32_16x16x32_bf16(afrag[1][0], b0, z4, 0, 0, 0);
      f32x4 q2 = __builtin_amdgcn_mfma_f32_16x16x32_bf16(afrag[2][0], b0, z4, 0, 0, 0);
      f32x4 q3 = __builtin_amdgcn_mfma_f32_16x16x32_bf16(afrag[3][0], b0, z4, 0, 0, 0);
      q0 = __builtin_amdgcn_mfma_f32_16x16x32_bf16(afrag[0][1], b1, q0, 0, 0, 0);
      q1 = __builtin_amdgcn_mfma_f32_16x16x32_bf16(afrag[1][1], b1, q1, 0, 0, 0);
      q2 = __builtin_amdgcn_mfma_f32_16x16x32_bf16(afrag[2][1], b1, q2, 0, 0, 0);
      q3 = __builtin_amdgcn_mfma_f32_16x16x32_bf16(afrag[3][1], b1, q3, 0, 0, 0);

      ps[0] = q0 * e0;
      ps[1] = q1 * e1;
      ps[2] = q2 * e2;
      ps[3] = q3 * e3;
    }

    // Renormalize by exact power of 2 (growth <= ~2^15/step, 4 steps safe).
    f32x4 m4 = max4(max4(ps[0], ps[1]), max4(ps[2], ps[3]));
    float m = fmaxf(fmaxf(m4.x, m4.y), fmaxf(m4.z, m4.w));
    m = fmaxf(m, __shfl_xor(m, 16));
    m = fmaxf(m, __shfl_xor(m, 32));
    const int e = (int)((__float_as_uint(m) >> 23) & 0xFFu) - 127;
    const float s = __uint_as_float((unsigned)(127 - e) << 23);  // exact 2^-e
#pragma unroll
    for (int mt = 0; mt < 4; ++mt) ps[mt] *= s;
    tot_e += (float)e;
  }

  // Tail steps (R in 0..3), consuming pre[0..R-1]; no renorm needed.
#pragma unroll
  for (int i = 0; i < 3; ++i) {
    if (i < R) {
      const bf16x8 b0 = pack_bfrag(ps[0], ps[1]);
      const bf16x8 b1 = pack_bfrag(ps[2], ps[3]);
      f32x4 q0 = __builtin_amdgcn_mfma_f32_16x16x32_bf16(afrag[0][0], b0, z4, 0, 0, 0);
      f32x4 q1 = __builtin_amdgcn_mfma_f32_16x16x32_bf16(afrag[1][0], b0, z4, 0, 0, 0);
      f32x4 q2 = __builtin_amdgcn_mfma_f32_16x16x32_bf16(afrag[2][0], b0, z4, 0, 0, 0);
      f32x4 q3 = __builtin_amdgcn_mfma_f32_16x16x32_bf16(afrag[3][0], b0, z4, 0, 0, 0);
      q0 = __builtin_amdgcn_mfma_f32_16x16x32_bf16(afrag[0][1], b1, q0, 0, 0, 0);
      q1 = __builtin_amdgcn_mfma_f32_16x16x32_bf16(afrag[1][1], b1, q1, 0, 0, 0);
      q2 = __builtin_amdgcn_mfma_f32_16x16x32_bf16(afrag[2][1], b1, q2, 0, 0, 0);
      q3 = __builtin_amdgcn_mfma_f32_16x16x32_bf16(afrag[3][1], b1, q3, 0, 0, 0);
      ps[0] = q0 * pre[i][0];
      ps[1] = q1 * pre[i][1];
      ps[2] = q2 * pre[i][2];
      ps[3] = q3 * pre[i][3];
    }
  }

  // Terminal: out[b] = tot_e*ln2 + ln( sum_row p[row] * exp(trans[END][row]) )
  float sum = 0.f;
#pragma unroll
  for (int mt = 0; mt < 4; ++mt) {
    sum += ps[mt].x * eend[mt][0];
    sum += ps[mt].y * eend[mt][1];
    sum += ps[mt].z * eend[mt][2];
    sum += ps[mt].w * eend[mt][3];
  }
  sum += __shfl_xor(sum, 16);
  sum += __shfl_xor(sum, 32);

  if (lane == 0) out[b] = tot_e * 0.69314718055994530942f + logf(sum);
}

extern "C" void kernel_launch(void* const* d_in, const int* in_sizes, int n_in,
                              void* d_out, int out_size, void* d_ws, size_t ws_size,
                              hipStream_t stream) {
  const float* unary = (const float*)d_in[0];  // [B, T, N] fp32
  const float* trans = (const float*)d_in[1];  // [N, N] fp32
  const int* lengths = (const int*)d_in[2];    // [B] int32
  float* out = (float*)d_out;                  // [B] fp32

  const size_t n = (size_t)kB * kT * kN;
  // eu = exp(unary): into workspace if it fits, else in-place over d_in[0]
  // (legal: harness restores inputs from pristine copies before every launch).
  float* eu = (ws_size >= n * sizeof(float)) ? (float*)d_ws : (float*)d_in[0];

  exp_pass_kernel<<<dim3(512), dim3(256), 0, stream>>>(unary, eu, (int)(n / 4));
  crf_mfma_kernel<<<dim3(kB), dim3(kN), 0, stream>>>(eu, trans, lengths, out);
}

// Round 3
// 500.838 us; speedup vs baseline: 1.4846x; 1.0481x over previous
//
#include <hip/hip_runtime.h>

// CRF forward (log partition), B=256, T=2048, N=64, MI355X.
//
// Round 3: MFMA recurrence (permuted-K A-fragments, zero-shuffle feedback) +
//  - eu stored as SWIZZLED bf16 (lane's 16 per-step values = 32 contiguous B)
//    -> register prefetch ring deepened 4 -> 16 steps (covers HBM latency)
//  - renorm via readfirstlane exponent (spread bound: entries within 2^18 of
//    max since E ratios <= e^1, eu ratios <= e^11) -> no cross-lane shuffles
//    in the serial chain.

typedef __attribute__((ext_vector_type(4))) float f32x4;
typedef __attribute__((ext_vector_type(8))) short bf16x8;

namespace {
constexpr int kB = 256;
constexpr int kT = 2048;
constexpr int kN = 64;
constexpr int kStart = 1;  // GO
constexpr int kEnd = 2;    // EOS
}  // namespace

// ---------- pre-pass: eu_sw[b][t][q4*16+mt*4+r] = bf16(exp(unary[b][t][mt*16+q4*4+r]))
// outStride = bytes per (b,t) row in the output (128 packed, 256 in-place).
// NOTE: may alias `in` (in-place fallback). Safe: each row's 32 pairs are
// processed by one wave; the row's loads (one instruction) complete before the
// stores issue (per-thread data dependency + SIMT lockstep program order).
__global__ void exp_swizzle_kernel(const float* in, char* outbase, int outStride) {
  const int total = kB * kT * 32;  // pairs
  int p = blockIdx.x * blockDim.x + threadIdx.x;
  const int stride = gridDim.x * blockDim.x;
  for (; p < total; p += stride) {
    const int r = p >> 5;
    const int j0 = (p & 31) << 1;
    const float2 v = *(const float2*)(in + (size_t)r * kN + j0);
    const float e0 = __expf(v.x), e1 = __expf(v.y);
    unsigned u0 = __float_as_uint(e0);
    u0 += 0x7FFFu + ((u0 >> 16) & 1u);  // RNE to bf16
    unsigned u1 = __float_as_uint(e1);
    u1 += 0x7FFFu + ((u1 >> 16) & 1u);
    const unsigned d = (u1 & 0xFFFF0000u) | (u0 >> 16);  // {bf(e1):bf(e0)}
    const int pi = ((j0 >> 2) & 3) * 16 + ((j0 >> 4) << 2) + (j0 & 3);
    *(unsigned*)(outbase + (size_t)r * outStride + pi * 2) = d;
  }
}

// ---------- main kernel helpers ----------
__device__ __forceinline__ unsigned pack2bf(float lo, float hi) {
  // dst = {hi.b3,hi.b2,lo.b3,lo.b2} = {bf16(hi) : bf16(lo)} (truncation)
  return __builtin_amdgcn_perm(__float_as_uint(hi), __float_as_uint(lo), 0x07060302u);
}

__device__ __forceinline__ bf16x8 pack_bfrag(f32x4 lo, f32x4 hi) {
  union { unsigned u[4]; bf16x8 s; } r;
  r.u[0] = pack2bf(lo.x, lo.y);
  r.u[1] = pack2bf(lo.z, lo.w);
  r.u[2] = pack2bf(hi.x, hi.y);
  r.u[3] = pack2bf(hi.z, hi.w);
  return r.s;
}

__device__ __forceinline__ f32x4 expand2(unsigned u, unsigned v) {
  f32x4 e;
  e.x = __uint_as_float(u << 16);
  e.y = __uint_as_float(u & 0xFFFF0000u);
  e.z = __uint_as_float(v << 16);
  e.w = __uint_as_float(v & 0xFFFF0000u);
  return e;
}

// One step: q = E*p (8 MFMA), p' = q .* eu  (eu given as 8 packed-bf16 dwords)
__device__ __forceinline__ void crf_step(f32x4 (&ps)[4], const bf16x8 (&af)[4][2],
                                         uint4 u0, uint4 u1) {
  const f32x4 e0 = expand2(u0.x, u0.y);
  const f32x4 e1 = expand2(u0.z, u0.w);
  const f32x4 e2 = expand2(u1.x, u1.y);
  const f32x4 e3 = expand2(u1.z, u1.w);

  const bf16x8 b0 = pack_bfrag(ps[0], ps[1]);
  const bf16x8 b1 = pack_bfrag(ps[2], ps[3]);
  const f32x4 z4 = {0.f, 0.f, 0.f, 0.f};

  f32x4 q0 = __builtin_amdgcn_mfma_f32_16x16x32_bf16(af[0][0], b0, z4, 0, 0, 0);
  f32x4 q1 = __builtin_amdgcn_mfma_f32_16x16x32_bf16(af[1][0], b0, z4, 0, 0, 0);
  f32x4 q2 = __builtin_amdgcn_mfma_f32_16x16x32_bf16(af[2][0], b0, z4, 0, 0, 0);
  f32x4 q3 = __builtin_amdgcn_mfma_f32_16x16x32_bf16(af[3][0], b0, z4, 0, 0, 0);
  q0 = __builtin_amdgcn_mfma_f32_16x16x32_bf16(af[0][1], b1, q0, 0, 0, 0);
  q1 = __builtin_amdgcn_mfma_f32_16x16x32_bf16(af[1][1], b1, q1, 0, 0, 0);
  q2 = __builtin_amdgcn_mfma_f32_16x16x32_bf16(af[2][1], b1, q2, 0, 0, 0);
  q3 = __builtin_amdgcn_mfma_f32_16x16x32_bf16(af[3][1], b1, q3, 0, 0, 0);

  ps[0] = q0 * e0;
  ps[1] = q1 * e1;
  ps[2] = q2 * e2;
  ps[3] = q3 * e3;
}

// Renormalize by exact power of 2 taken from lane 0's ps[0].x exponent.
// Spread bound: every entry within ~2^18 of the max, so reference exponent is
// within 18 of max; 4-step growth <= 2^59 -> max stays < 2^78. No shuffles.
__device__ __forceinline__ void renorm(f32x4 (&ps)[4], float& tot_e) {
  const unsigned eref = __builtin_amdgcn_readfirstlane(__float_as_uint(ps[0].x));
  const int e = (int)((eref >> 23) & 0xFFu) - 127;
  const float sc = __uint_as_float((unsigned)(127 - e) << 23);  // exact 2^-e
#pragma unroll
  for (int mt = 0; mt < 4; ++mt) ps[mt] *= sc;
  tot_e += (float)e;
}

template <int S>  // S = eu row stride in bytes (128 packed, 256 in-place)
__global__ __launch_bounds__(64, 1) void crf_mfma_kernel(
    const char* __restrict__ eu, const float* __restrict__ trans,
    const int* __restrict__ lengths, float* __restrict__ out) {
  const int b = blockIdx.x;
  const int lane = threadIdx.x;
  const int col = lane & 15;
  const int q4 = lane >> 4;
  const int len = lengths[b];

  // Static A-fragments with permuted K: A[m][psi(kc,j)] = bf16(exp(trans[m][k])),
  // psi(kc,j) = (2kc+(j>>2))*16 + q4*4 + (j&3). (Verified in round 2.)
  bf16x8 af[4][2];
#pragma unroll
  for (int mt = 0; mt < 4; ++mt) {
#pragma unroll
    for (int kc = 0; kc < 2; ++kc) {
      union { unsigned u[4]; bf16x8 s; } fr;
#pragma unroll
      for (int jp = 0; jp < 4; ++jp) {
        const int j0 = 2 * jp, j1 = 2 * jp + 1;
        const int k0 = (2 * kc + (j0 >> 2)) * 16 + q4 * 4 + (j0 & 3);
        const int k1 = (2 * kc + (j1 >> 2)) * 16 + q4 * 4 + (j1 & 3);
        unsigned e0 = __float_as_uint(__expf(trans[(mt * 16 + col) * kN + k0])) + 0x8000u;
        unsigned e1 = __float_as_uint(__expf(trans[(mt * 16 + col) * kN + k1])) + 0x8000u;
        fr.u[jp] = __builtin_amdgcn_perm(e1, e0, 0x07060302u);
      }
      af[mt][kc] = fr.s;
    }
  }

  // p one-hot at START=1 (mt=0, q4=0, r=1), replicated over the 16 columns.
  f32x4 ps[4];
#pragma unroll
  for (int mt = 0; mt < 4; ++mt) ps[mt] = (f32x4){0.f, 0.f, 0.f, 0.f};
  if (q4 == 0) ps[0].y = 1.0f;

  // eu prefetch ring: 4 groups x 4 steps x 8 dwords (32 B/step/lane).
  const char* base = eu + (size_t)b * kT * S + q4 * 32;
  uint4 pre[4][4][2];
#pragma unroll
  for (int g = 0; g < 4; ++g)
#pragma unroll
    for (int i = 0; i < 4; ++i) {
      pre[g][i][0] = *(const uint4*)(base + (size_t)(g * 4 + i) * S);
      pre[g][i][1] = *(const uint4*)(base + (size_t)(g * 4 + i) * S + 16);
    }

  size_t pfOff = (size_t)16 * S;              // next prefetch = t 16..19
  const size_t pfMax = (size_t)(kT - 4) * S;  // clamp (rows 2044..2047)
  float tot_e = 0.0f;

  const int SG = len >> 4;  // superblocks of 16 steps; len >= 1024 -> SG >= 64
  for (int s = 0; s < SG; ++s) {
#pragma unroll
    for (int g = 0; g < 4; ++g) {
      crf_step(ps, af, pre[g][0][0], pre[g][0][1]);
      crf_step(ps, af, pre[g][1][0], pre[g][1][1]);
      crf_step(ps, af, pre[g][2][0], pre[g][2][1]);
      crf_step(ps, af, pre[g][3][0], pre[g][3][1]);
      // Refill this slot with the group 4 ahead (clamped rows never consumed).
      const char* pf = base + pfOff;
#pragma unroll
      for (int i = 0; i < 4; ++i) {
        pre[g][i][0] = *(const uint4*)(pf + (size_t)i * S);
        pre[g][i][1] = *(const uint4*)(pf + (size_t)i * S + 16);
      }
      pfOff += (size_t)4 * S;
      if (pfOff > pfMax) pfOff = pfMax;
      renorm(ps, tot_e);
    }
  }

  // Epilogue: ring already holds the next 16 steps (t = 16*SG ..). rem <= 15.
  const int rem = len & 15;
#pragma unroll
  for (int g = 0; g < 4; ++g) {
    if (rem >= (g + 1) * 4) {
      crf_step(ps, af, pre[g][0][0], pre[g][0][1]);
      crf_step(ps, af, pre[g][1][0], pre[g][1][1]);
      crf_step(ps, af, pre[g][2][0], pre[g][2][1]);
      crf_step(ps, af, pre[g][3][0], pre[g][3][1]);
      renorm(ps, tot_e);
    }
  }
  const int pg = rem >> 2, pr = rem & 3;
#pragma unroll
  for (int g = 0; g < 4; ++g) {
    if (pg == g && pr > 0) {
      crf_step(ps, af, pre[g][0][0], pre[g][0][1]);
      if (pr > 1) crf_step(ps, af, pre[g][1][0], pre[g][1][1]);
      if (pr > 2) crf_step(ps, af, pre[g][2][0], pre[g][2][1]);
    }
  }

  // Terminal: out[b] = tot_e*ln2 + ln( sum_row p[row] * exp(trans[END][row]) )
  float sum = 0.f;
#pragma unroll
  for (int mt = 0; mt < 4; ++mt) {
    const int rbase = kEnd * kN + mt * 16 + q4 * 4;
    sum += ps[mt].x * __expf(trans[rbase + 0]);
    sum += ps[mt].y * __expf(trans[rbase + 1]);
    sum += ps[mt].z * __expf(trans[rbase + 2]);
    sum += ps[mt].w * __expf(trans[rbase + 3]);
  }
  sum += __shfl_xor(sum, 16);
  sum += __shfl_xor(sum, 32);

  if (lane == 0) out[b] = tot_e * 0.69314718055994530942f + logf(sum);
}

extern "C" void kernel_launch(void* const* d_in, const int* in_sizes, int n_in,
                              void* d_out, int out_size, void* d_ws, size_t ws_size,
                              hipStream_t stream) {
  const float* unary = (const float*)d_in[0];  // [B, T, N] fp32
  const float* trans = (const float*)d_in[1];  // [N, N] fp32
  const int* lengths = (const int*)d_in[2];    // [B] int32
  float* out = (float*)d_out;                  // [B] fp32

  const size_t needed = (size_t)kB * kT * kN * 2;  // 64 MiB bf16 swizzled eu
  if (ws_size >= needed) {
    exp_swizzle_kernel<<<dim3(4096), dim3(256), 0, stream>>>(
        unary, (char*)d_ws, 128);
    crf_mfma_kernel<128><<<dim3(kB), dim3(64), 0, stream>>>(
        (const char*)d_ws, trans, lengths, out);
  } else {
    // In-place fallback: bf16 rows packed into the first 128 B of each 256-B
    // f32 row (harness restores inputs before every launch).
    exp_swizzle_kernel<<<dim3(4096), dim3(256), 0, stream>>>(
        unary, (char*)d_in[0], 256);
    crf_mfma_kernel<256><<<dim3(kB), dim3(64), 0, stream>>>(
        (const char*)d_in[0], trans, lengths, out);
  }
}